// Round 2
// baseline (452.657 us; speedup 1.0000x reference)
//
#include <hip/hip_runtime.h>

#define L  2048
#define D  64
#define NH 16
#define NB 2

using half8   = _Float16 __attribute__((ext_vector_type(8)));
using half4v  = _Float16 __attribute__((ext_vector_type(4)));
using float4v = float    __attribute__((ext_vector_type(4)));
using int4v   = int      __attribute__((ext_vector_type(4)));

// ---------------- precompute: qh = fp16(q/8), kh = fp16(k) ----------------
__global__ __launch_bounds__(256) void prep_qk(const float* __restrict__ q,
                                               const float* __restrict__ k,
                                               _Float16* __restrict__ qh,
                                               _Float16* __restrict__ kh) {
    int i = (blockIdx.x * 256 + threadIdx.x) * 8;
    float4v a0 = *(const float4v*)(q + i);
    float4v a1 = *(const float4v*)(q + i + 4);
    float4v b0 = *(const float4v*)(k + i);
    float4v b1 = *(const float4v*)(k + i + 4);
    half8 qo, ko;
#pragma unroll
    for (int j = 0; j < 4; ++j) {
        qo[j]     = (_Float16)(a0[j] * 0.125f);   // fold 1/TEMPERATURE
        qo[4 + j] = (_Float16)(a1[j] * 0.125f);
        ko[j]     = (_Float16)b0[j];
        ko[4 + j] = (_Float16)b1[j];
    }
    *(half8*)(qh + i) = qo;
    *(half8*)(kh + i) = ko;
}

// ---------------- precompute: vt[b,h,d,l] = fp16(v[b,h,l,d]) ----------------
__global__ __launch_bounds__(256) void prep_vt(const float* __restrict__ v,
                                               _Float16* __restrict__ vt) {
    __shared__ float tile[64][65];
    int bh = blockIdx.x >> 5;          // 0..31
    int l0 = (blockIdx.x & 31) * 64;
    const float* vb = v + (size_t)bh * L * D + (size_t)l0 * D;
    int row = threadIdx.x >> 2, c0 = (threadIdx.x & 3) * 16;
#pragma unroll
    for (int j = 0; j < 16; j += 4) {
        float4v t4 = *(const float4v*)(vb + row * D + c0 + j);
        tile[row][c0 + j + 0] = t4[0];
        tile[row][c0 + j + 1] = t4[1];
        tile[row][c0 + j + 2] = t4[2];
        tile[row][c0 + j + 3] = t4[3];
    }
    __syncthreads();
    int d = threadIdx.x >> 2, lq = (threadIdx.x & 3) * 16;
    _Float16* ob = vt + (size_t)bh * D * L + (size_t)d * L + l0 + lq;
    half8 o0, o1;
#pragma unroll
    for (int j = 0; j < 8; ++j) {
        o0[j] = (_Float16)tile[lq + j][d];
        o1[j] = (_Float16)tile[lq + 8 + j][d];
    }
    *(half8*)(ob)     = o0;
    *(half8*)(ob + 8) = o1;
}

// ---------------- main attention kernel ----------------
// block = (b, h, qtile of 16 rows), 256 threads = 4 waves; wave w owns keys
// [512w, 512w+512). SWAPPED QK^T: mfma(K,Q) -> C[row=key][col=q-row], so each
// lane holds 4 CONSECUTIVE keys (grp*4+r) of ONE q-row (cg). This makes
// mask/bias int4/float4 loads, attn writes float4-from-register, and the
// row-sum a 2-shfl reduce.
__global__ __launch_bounds__(256, 2) void attn_main(const _Float16* __restrict__ qh,
                                                    const _Float16* __restrict__ kh,
                                                    const _Float16* __restrict__ vt,
                                                    const int* __restrict__ mask,
                                                    const float* __restrict__ bias,
                                                    float* __restrict__ out_ho,
                                                    float* __restrict__ out_attn) {
    __shared__ _Float16 P[16 * 2048];     // 64 KiB, XOR-swizzled rows
    __shared__ float lpart[4][16];

    // XCD-chunked swizzle (hw xcd = blockIdx % 8): each XCD gets one (b,h2)
    // group -> kh/vt for 4 heads (2 MB) + their mask/bias slices L2-resident.
    int p  = blockIdx.x;
    int l  = (p & 7) * 512 + (p >> 3);
    int h1 = l & 3, qt = (l >> 2) & 127, h2 = (l >> 9) & 3, b = l >> 11;
    int h  = h2 * 4 + h1;
    int bh = b * NH + h;
    int q0 = qt * 16;

    int tid = threadIdx.x, w = tid >> 6, lane = tid & 63;
    int cg = lane & 15, grp = lane >> 4;

    const _Float16* qbase = qh + ((size_t)bh * L + q0) * D;
    const _Float16* kbase = kh + (size_t)bh * L * D;
    const _Float16* vbase = vt + (size_t)bh * D * L;

    // Q-frag (B-operand): Q[q-row=cg][k=grp*8+j]
    half8 aq0 = *(const half8*)(qbase + cg * D + grp * 8);
    half8 aq1 = *(const half8*)(qbase + cg * D + 32 + grp * 8);

    int k0w = w * 512;
    const size_t mrow = ((size_t)b * L + (q0 + cg)) * L;   // this lane's q-row in mask/bias

    float4v pu[32];
    float ls = 0.f;
#pragma unroll
    for (int f = 0; f < 32; ++f) {
        int n0 = k0w + f * 16;
        const _Float16* kb = kbase + (size_t)(n0 + cg) * D + grp * 8;
        half8 bk0 = *(const half8*)(kb);        // K-frag (A): K[key=cg][k]
        half8 bk1 = *(const half8*)(kb + 32);
        int4v   m4 = *(const int4v*)(mask + mrow + n0 + grp * 4);
        float4v b4 = *(const float4v*)(bias + mrow + n0 + grp * 4);
        float4v acc;
        acc[0] = m4[0] ? b4[0] : -1e9f;
        acc[1] = m4[1] ? b4[1] : -1e9f;
        acc[2] = m4[2] ? b4[2] : -1e9f;
        acc[3] = m4[3] ? b4[3] : -1e9f;
        // swapped: C[row=key=n0+grp*4+r][col=q-row=cg]
        acc = __builtin_amdgcn_mfma_f32_16x16x32_f16(bk0, aq0, acc, 0, 0, 0);
        acc = __builtin_amdgcn_mfma_f32_16x16x32_f16(bk1, aq1, acc, 0, 0, 0);
        float4v e;
        e[0] = __expf(acc[0]); e[1] = __expf(acc[1]);
        e[2] = __expf(acc[2]); e[3] = __expf(acc[3]);
        ls += (e[0] + e[1]) + (e[2] + e[3]);
        pu[f] = e;
    }

    // row-sum: sum over the 4 groups (lanes cg, cg+16, cg+32, cg+48)
    ls += __shfl_xor(ls, 16);
    ls += __shfl_xor(ls, 32);
    if (grp == 0) lpart[w][cg] = ls;
    __syncthreads();
    float rl = 1.0f / (lpart[0][cg] + lpart[1][cg] + lpart[2][cg] + lpart[3][cg]);

    // normalize: write attn directly from regs (fp32), stage P in LDS (fp16)
    char* Pb = (char*)P;
    float* abase = out_attn + ((size_t)bh * L + (q0 + cg)) * L;
    int rowoff = cg << 12;          // 4096 B per P row
    int swz    = (cg & 3) << 5;     // XOR bits 5-6: bank-optimal b64 write + b128 read
#pragma unroll
    for (int f = 0; f < 32; ++f) {
        int key = k0w + f * 16 + grp * 4;
        float4v pn;
        pn[0] = pu[f][0] * rl; pn[1] = pu[f][1] * rl;
        pn[2] = pu[f][2] * rl; pn[3] = pu[f][3] * rl;
        *(float4v*)(abase + key) = pn;              // 4 consecutive keys, fp32
        half4v ph;
        ph[0] = (_Float16)pn[0]; ph[1] = (_Float16)pn[1];
        ph[2] = (_Float16)pn[2]; ph[3] = (_Float16)pn[3];
        *(half4v*)(Pb + (rowoff + (((key << 1)) ^ swz))) = ph;
    }
    __syncthreads();

    // PV: wave w owns d-slice [16w,16w+16), full key range from LDS P.
    // 4 independent accumulators break the serial MFMA chain.
    int d0 = w * 16;
    const _Float16* vb = vbase + (size_t)(d0 + cg) * L;
    float4v oa0 = {0.f,0.f,0.f,0.f}, oa1 = {0.f,0.f,0.f,0.f};
    float4v oa2 = {0.f,0.f,0.f,0.f}, oa3 = {0.f,0.f,0.f,0.f};
#pragma unroll
    for (int kc = 0; kc < 64; kc += 4) {
        half8 pa0 = *(const half8*)(Pb + (rowoff + ((((kc+0) << 6) + (grp << 4)) ^ swz)));
        half8 pa1 = *(const half8*)(Pb + (rowoff + ((((kc+1) << 6) + (grp << 4)) ^ swz)));
        half8 pa2 = *(const half8*)(Pb + (rowoff + ((((kc+2) << 6) + (grp << 4)) ^ swz)));
        half8 pa3 = *(const half8*)(Pb + (rowoff + ((((kc+3) << 6) + (grp << 4)) ^ swz)));
        half8 pb0 = *(const half8*)(vb + (kc+0) * 32 + grp * 8);
        half8 pb1 = *(const half8*)(vb + (kc+1) * 32 + grp * 8);
        half8 pb2 = *(const half8*)(vb + (kc+2) * 32 + grp * 8);
        half8 pb3 = *(const half8*)(vb + (kc+3) * 32 + grp * 8);
        oa0 = __builtin_amdgcn_mfma_f32_16x16x32_f16(pa0, pb0, oa0, 0, 0, 0);
        oa1 = __builtin_amdgcn_mfma_f32_16x16x32_f16(pa1, pb1, oa1, 0, 0, 0);
        oa2 = __builtin_amdgcn_mfma_f32_16x16x32_f16(pa2, pb2, oa2, 0, 0, 0);
        oa3 = __builtin_amdgcn_mfma_f32_16x16x32_f16(pa3, pb3, oa3, 0, 0, 0);
    }
    float4v oacc;
    oacc[0] = (oa0[0] + oa1[0]) + (oa2[0] + oa3[0]);
    oacc[1] = (oa0[1] + oa1[1]) + (oa2[1] + oa3[1]);
    oacc[2] = (oa0[2] + oa1[2]) + (oa2[2] + oa3[2]);
    oacc[3] = (oa0[3] + oa1[3]) + (oa2[3] + oa3[3]);

    float* obase = out_ho + ((size_t)bh * L + q0) * D + d0;
    obase[(size_t)(grp * 4 + 0) * D + cg] = oacc[0];
    obase[(size_t)(grp * 4 + 1) * D + cg] = oacc[1];
    obase[(size_t)(grp * 4 + 2) * D + cg] = oacc[2];
    obase[(size_t)(grp * 4 + 3) * D + cg] = oacc[3];
}

extern "C" void kernel_launch(void* const* d_in, const int* in_sizes, int n_in,
                              void* d_out, int out_size, void* d_ws, size_t ws_size,
                              hipStream_t stream) {
    const float* q    = (const float*)d_in[0];
    const float* k    = (const float*)d_in[1];
    const float* v    = (const float*)d_in[2];
    const int*   mask = (const int*)d_in[3];
    const float* bias = (const float*)d_in[4];

    float* ho   = (float*)d_out;
    float* attn = (float*)d_out + (size_t)NB * NH * L * D;

    char* ws = (char*)d_ws;
    _Float16* qh = (_Float16*)(ws);                       // 8 MB
    _Float16* kh = (_Float16*)(ws + ((size_t)8  << 20));  // 8 MB
    _Float16* vt = (_Float16*)(ws + ((size_t)16 << 20));  // 8 MB
    (void)in_sizes; (void)n_in; (void)out_size; (void)ws_size;

    prep_qk<<<2048, 256, 0, stream>>>(q, k, qh, kh);
    prep_vt<<<1024, 256, 0, stream>>>(v, vt);
    attn_main<<<4096, 256, 0, stream>>>(qh, kh, vt, mask, bias, ho, attn);
}